// Round 2
// baseline (461.809 us; speedup 1.0000x reference)
//
#include <hip/hip_runtime.h>
#include <math.h>

#define DIM    512
#define HEADS  8
#define DK     32
#define NKEYS  256
#define PKTOP  16
#define NTOK   1024   // b*n = 2*512

// gelu (tanh approx, matches flax approximate gelu)
__device__ __forceinline__ float gelu_t(float x)
{
    float x3 = x * x * x;
    return 0.5f * x * (1.f + tanhf(0.7978845608028654f * (x + 0.044715f * x3)));
}

// ------------- 2-wave k-split fp32 GEMM, 32x32 tile, 4x4 per lane -----------
// A: [M,K] row-major. B: [K,N] row-major (BT=false) or [N,K] row-major (BT=true).
// Block = 128 threads = 2 waves. Wave w computes the partial sum over
// K-range [w*T*64, (w+1)*T*64) (T = K/128 tiles of BK=64), using its own
// private LDS buffers -> NO barriers in the main loop. Global->reg loads for
// tile t+1 are issued before the compute of tile t (prefetch; ~2048 cyc of
// FMA hides HBM latency). Cross-wave reduce via LDS + one __syncthreads.
// EPI==0: C = scale*acc.  EPI==1: C = gelu(acc) * WS[m][n]  (WS [M,N] rm).
// ZW: block zeroes 512 floats of WS at offset bid*512 (wsum init for k2).
// Fragment reads As[w][k][mg*4] / Bs[w][k][ng*4] are 8-way lane broadcasts
// (128 B unique, all 32 banks exactly once) -> conflict-free, ~4 cyc each.
template<bool BT, int EPI, bool ZW, int T>
__global__ __launch_bounds__(128)
void wgemm2(const float* __restrict__ A, const float* __restrict__ B,
            float* __restrict__ C, int M, int N, int K, float scale,
            float* __restrict__ WS)
{
    __shared__ float As[2][64][36];   // [wave][k][m], stride 36 (16B-aligned rows)
    __shared__ float Bs[2][64][36];   // [wave][k][n]
    __shared__ float red[32][36];     // wave1 -> wave0 partial-sum handoff

    const int tid  = threadIdx.x;
    const int w    = tid >> 6;        // wave 0/1
    const int lane = tid & 63;
    const int mg   = lane >> 3;       // 0..7
    const int ng   = lane & 7;        // 0..7
    const int m0   = blockIdx.y * 32;
    const int n0   = blockIdx.x * 32;

    if (ZW) {
        const int bid = blockIdx.y * gridDim.x + blockIdx.x;
        *(float4*)(WS + (size_t)bid * 512 + tid * 4) = make_float4(0.f, 0.f, 0.f, 0.f);
    }

    const int r16 = lane >> 4;        // 0..3
    const int c16 = lane & 15;        // 0..15
    const int r8  = lane >> 3;        // 0..7
    const int c8  = lane & 7;         // 0..7
    const int kb0 = w * (T * 64);     // this wave's K base

    // global -> regs (16 float4 per tile, double-banked for prefetch)
    auto loadAB = [&](float4 (&da)[8], float4 (&db)[8], int kbase) {
#pragma unroll
        for (int it = 0; it < 8; ++it)
            da[it] = *(const float4*)(A + (size_t)(m0 + r16 + 4 * it) * K + kbase + c16 * 4);
        if (!BT) {
#pragma unroll
            for (int it = 0; it < 8; ++it)
                db[it] = *(const float4*)(B + (size_t)(kbase + r8 + 8 * it) * N + n0 + c8 * 4);
        } else {
#pragma unroll
            for (int it = 0; it < 8; ++it)
                db[it] = *(const float4*)(B + (size_t)(n0 + r16 + 4 * it) * K + kbase + c16 * 4);
        }
    };
    // regs -> this wave's private LDS tile (A transposed; B transposed iff BT)
    auto storeAB = [&](const float4 (&da)[8], const float4 (&db)[8]) {
#pragma unroll
        for (int it = 0; it < 8; ++it) {
            int row = r16 + 4 * it;
            As[w][c16 * 4 + 0][row] = da[it].x; As[w][c16 * 4 + 1][row] = da[it].y;
            As[w][c16 * 4 + 2][row] = da[it].z; As[w][c16 * 4 + 3][row] = da[it].w;
        }
        if (!BT) {
#pragma unroll
            for (int it = 0; it < 8; ++it)
                *(float4*)&Bs[w][r8 + 8 * it][c8 * 4] = db[it];
        } else {
#pragma unroll
            for (int it = 0; it < 8; ++it) {
                int nr = r16 + 4 * it;
                Bs[w][c16 * 4 + 0][nr] = db[it].x; Bs[w][c16 * 4 + 1][nr] = db[it].y;
                Bs[w][c16 * 4 + 2][nr] = db[it].z; Bs[w][c16 * 4 + 3][nr] = db[it].w;
            }
        }
    };

    float acc[4][4] = {{0.f}};
    float4 av[2][8], bv[2][8];

    loadAB(av[0], bv[0], kb0);
#pragma unroll
    for (int t = 0; t < T; ++t) {
        storeAB(av[t & 1], bv[t & 1]);                        // waits vmcnt per-reg
        if (t + 1 < T)
            loadAB(av[(t + 1) & 1], bv[(t + 1) & 1], kb0 + (t + 1) * 64);  // flies under compute
#pragma unroll
        for (int k = 0; k < 64; ++k) {
            float4 a = *(const float4*)&As[w][k][mg * 4];     // 8-lane broadcast
            float4 b = *(const float4*)&Bs[w][k][ng * 4];
            float af[4] = {a.x, a.y, a.z, a.w};
            float bf[4] = {b.x, b.y, b.z, b.w};
#pragma unroll
            for (int i = 0; i < 4; ++i)
#pragma unroll
                for (int j = 0; j < 4; ++j) acc[i][j] += af[i] * bf[j];
        }
        // next iteration's storeAB overwrites As/Bs[w]; per-wave in-order LDS
        // pipe (reads above already issued) makes this WAR-safe, no barrier.
    }

    // cross-wave K-reduce: wave1 dumps partials, wave0 combines + epilogue
    if (w == 1) {
#pragma unroll
        for (int i = 0; i < 4; ++i)
            *(float4*)&red[mg * 4 + i][ng * 4] =
                make_float4(acc[i][0], acc[i][1], acc[i][2], acc[i][3]);
    }
    __syncthreads();
    if (w == 0) {
#pragma unroll
        for (int i = 0; i < 4; ++i) {
            float4 r = *(const float4*)&red[mg * 4 + i][ng * 4];
            float s0 = acc[i][0] + r.x, s1 = acc[i][1] + r.y;
            float s2 = acc[i][2] + r.z, s3 = acc[i][3] + r.w;
            int m = m0 + mg * 4 + i;
            float4 o;
            if (EPI == 1) {
                float4 ww = *(const float4*)(WS + (size_t)m * N + n0 + ng * 4);
                o.x = gelu_t(s0) * ww.x; o.y = gelu_t(s1) * ww.y;
                o.z = gelu_t(s2) * ww.z; o.w = gelu_t(s3) * ww.w;
            } else {
                o = make_float4(s0 * scale, s1 * scale, s2 * scale, s3 * scale);
            }
            *(float4*)(C + (size_t)m * N + n0 + ng * 4) = o;
        }
    }
}

// ---------------- sim + double top-16 + softmax -> atomic wsum --------------
// Wave-wide argmax with lax.top_k tie semantics: max value; on tie, lowest
// flat index wins. Flat index = lane*4 + slot. The softmax weight is
// atomically accumulated into wsum[token][expert] (wsum pre-zeroed by the
// q-GEMM kernel), killing the scatter pass in the down-projection kernel.
__global__ __launch_bounds__(256)
void k_simtopk(const float* __restrict__ q, const float* __restrict__ keys,
               float* __restrict__ wsum)
{
    const int lane = threadIdx.x & 63;
    const int th   = blockIdx.x * 4 + (threadIdx.x >> 6);   // token-head 0..8191
    const int t    = th >> 3;
    const int hh   = th & 7;
    const int base = lane * 4;

    // wave-uniform q sub-row (p=0 half): cols hh*32 .. hh*32+31
    const float4* qv = (const float4*)(q + (size_t)t * DIM + hh * DK);
    float4 qr[8];
#pragma unroll
    for (int i = 0; i < 8; ++i) qr[i] = qv[i];

    // 4 keys per lane: k = base + j ;  keys[h][k][0][d]
    float v1[4];
#pragma unroll
    for (int j = 0; j < 4; ++j) {
        int k = base + j;
        const float4* kv = (const float4*)(keys + ((size_t)hh * NKEYS + k) * 2 * DK);
        float s = 0.f;
#pragma unroll
        for (int i = 0; i < 8; ++i) {
            float4 kk = kv[i];
            s += kk.x * qr[i].x + kk.y * qr[i].y + kk.z * qr[i].z + kk.w * qr[i].w;
        }
        v1[j] = s;
    }

    // stage 1: top-16 of sim. Per-lane captures for stage 2:
    //   lane l needs v0[l>>2] and i0[4*(l&3)+jj], jj=0..3
    float my_v0 = 0.f;
    int   my_i0[4] = {0, 0, 0, 0};
#pragma unroll
    for (int r = 0; r < 16; ++r) {
        float b = v1[0]; int bj = 0;
        if (v1[1] > b) { b = v1[1]; bj = 1; }
        if (v1[2] > b) { b = v1[2]; bj = 2; }
        if (v1[3] > b) { b = v1[3]; bj = 3; }
        float m = b;
#pragma unroll
        for (int off = 32; off; off >>= 1) m = fmaxf(m, __shfl_xor(m, off, 64));
        unsigned long long bal = __ballot(b == m);
        int wl   = __ffsll((long long)bal) - 1;
        int widx = __shfl(base + bj, wl, 64);
        if ((lane >> 2) == r)       my_v0        = m;
        if ((lane & 3) == (r >> 2)) my_i0[r & 3] = widx;
        if (lane == wl) v1[bj] = -INFINITY;
    }

    // stage 2: candidate c = base+jj == 16*i + j with i=c>>4, j=c&15
    float v2[4];
#pragma unroll
    for (int jj = 0; jj < 4; ++jj) v2[jj] = my_v0 + (float)my_i0[jj];

    float sc0 = 0.f, ssum = 0.f, my_sc = 0.f;
    int   my_pk = 0;
#pragma unroll
    for (int r = 0; r < 16; ++r) {
        float b = v2[0]; int bj = 0;
        if (v2[1] > b) { b = v2[1]; bj = 1; }
        if (v2[2] > b) { b = v2[2]; bj = 2; }
        if (v2[3] > b) { b = v2[3]; bj = 3; }
        float m = b;
#pragma unroll
        for (int off = 32; off; off >>= 1) m = fmaxf(m, __shfl_xor(m, off, 64));
        unsigned long long bal = __ballot(b == m);
        int wl = __ffsll((long long)bal) - 1;
        int wc = __shfl(base + bj, wl, 64);
        if (r == 0) sc0 = m;              // round-0 winner is the max
        ssum += expf(m - sc0);
        if (lane == r) { my_sc = m; my_pk = wc; }
        if (lane == wl) v2[bj] = -INFINITY;
    }
    if (lane < PKTOP)
        atomicAdd(&wsum[(size_t)t * NKEYS + my_pk], expf(my_sc - sc0) / ssum);
}

// ---------------- launch ----------------
extern "C" void kernel_launch(void* const* d_in, const int* in_sizes, int n_in,
                              void* d_out, int out_size, void* d_ws, size_t ws_size,
                              hipStream_t stream)
{
    const float* x    = (const float*)d_in[0];   // [1024, 512]
    const float* wq   = (const float*)d_in[1];   // [512, 512]
    const float* keys = (const float*)d_in[2];   // [8, 256, 2, 32]
    const float* wd   = (const float*)d_in[3];   // [65536, 512] (rows 0..255 used)
    const float* wu   = (const float*)d_in[4];   // [65536, 512] (rows 0..255 used)
    float* out = (float*)d_out;                  // [1024, 512]

    float* q    = (float*)d_ws;                  // 1024*512
    float* Cb   = q + NTOK * DIM;                // 1024*256
    float* wsum = Cb + NTOK * NKEYS;             // 1024*256

    const float bnscale = 1.0f / sqrtf(1.0f + 1e-5f);

    // q = (x @ wq) * bnscale  [1024 x 512], K=512 (T=4); also zeroes wsum
    wgemm2<false, 0, true, 4>
        <<<dim3(DIM / 32, NTOK / 32), 128, 0, stream>>>(x, wq, q, NTOK, DIM, DIM,
                                                        bnscale, wsum);

    // sim + double top-16 + softmax -> atomic accumulate into wsum[t][e]
    k_simtopk<<<dim3(NTOK * HEADS / 4), 256, 0, stream>>>(q, keys, wsum);

    // Cb[t,e] = gelu(q . wd[e]) * wsum[t,e]   [1024 x 256], K=512 (T=4), B^T
    wgemm2<true, 1, false, 4>
        <<<dim3(NKEYS / 32, NTOK / 32), 128, 0, stream>>>(q, wd, Cb, NTOK, NKEYS,
                                                          DIM, 1.f, wsum);

    // out = Cb @ wu[0:256]   [1024 x 512], K=256 (T=2)
    wgemm2<false, 0, false, 2>
        <<<dim3(DIM / 32, NTOK / 32), 128, 0, stream>>>(Cb, wu, out, NTOK, DIM,
                                                        NKEYS, 1.f, (float*)nullptr);
}

// Round 3
// 322.375 us; speedup vs baseline: 1.4325x; 1.4325x over previous
//
#include <hip/hip_runtime.h>
#include <math.h>

#define DIM    512
#define HEADS  8
#define DK     32
#define NKEYS  256
#define PKTOP  16
#define NTOK   1024   // b*n = 2*512

// gelu (tanh approx, matches flax approximate gelu)
__device__ __forceinline__ float gelu_t(float x)
{
    float x3 = x * x * x;
    return 0.5f * x * (1.f + tanhf(0.7978845608028654f * (x + 0.044715f * x3)));
}

// ---------------- generic fp32 tiled GEMM (round-0 proven structure) --------
// A: [M,K] row-major. B: [K,N] row-major (BT=false) or [N,K] row-major (BT=true).
// EPI==0: C = scale*acc.  EPI==1: C = gelu(acc) * WS[m][n]  (WS is [M,N] rm).
// ZW: block zeroes 1024 floats of WS at offset bid*1024 (wsum init; k1 grid
// is 256 blocks x 1024 floats = the full 1024x256 wsum).
template<int BM, int BN, int BK, int TM, int TN, bool BT, int EPI, bool ZW>
__global__ __launch_bounds__(256)
void sgemm(const float* __restrict__ A, const float* __restrict__ B,
           float* __restrict__ C, int M, int N, int K, float scale,
           float* __restrict__ WS)
{
    __shared__ float As[BK][BM + 4];
    __shared__ float Bs[BK][BN + 4];
    const int tid = threadIdx.x;
    const int tx  = tid & 15;
    const int ty  = tid >> 4;
    const int m0  = blockIdx.y * BM;
    const int n0  = blockIdx.x * BN;

    if (ZW) {
        const int bid = blockIdx.y * gridDim.x + blockIdx.x;
        *(float4*)(WS + (size_t)bid * 1024 + tid * 4) = make_float4(0.f, 0.f, 0.f, 0.f);
    }

    float acc[TM][TN];
#pragma unroll
    for (int i = 0; i < TM; ++i)
#pragma unroll
        for (int j = 0; j < TN; ++j) acc[i][j] = 0.f;

    for (int k0 = 0; k0 < K; k0 += BK) {
        // stage A tile (transposed): As[k][m] = A[m0+m][k0+k]
#pragma unroll
        for (int it = 0; it < (BM * BK / 4) / 256; ++it) {
            int L   = tid + 256 * it;
            int row = L / (BK / 4), kq = L % (BK / 4);
            float4 v = *(const float4*)(A + (size_t)(m0 + row) * K + k0 + kq * 4);
            As[kq * 4 + 0][row] = v.x; As[kq * 4 + 1][row] = v.y;
            As[kq * 4 + 2][row] = v.z; As[kq * 4 + 3][row] = v.w;
        }
        if (!BT) {
#pragma unroll
            for (int it = 0; it < (BK * BN / 4) / 256; ++it) {
                int L = tid + 256 * it;
                int k = L / (BN / 4), nq = L % (BN / 4);
                float4 v = *(const float4*)(B + (size_t)(k0 + k) * N + n0 + nq * 4);
                *(float4*)&Bs[k][nq * 4] = v;
            }
        } else {
#pragma unroll
            for (int it = 0; it < (BN * BK / 4) / 256; ++it) {
                int L = tid + 256 * it;
                int n = L / (BK / 4), kq = L % (BK / 4);
                float4 v = *(const float4*)(B + (size_t)(n0 + n) * K + k0 + kq * 4);
                Bs[kq * 4 + 0][n] = v.x; Bs[kq * 4 + 1][n] = v.y;
                Bs[kq * 4 + 2][n] = v.z; Bs[kq * 4 + 3][n] = v.w;
            }
        }
        __syncthreads();
#pragma unroll
        for (int k = 0; k < BK; ++k) {
            float a[TM], b[TN];
#pragma unroll
            for (int i = 0; i < TM; ++i) a[i] = As[k][ty * TM + i];
#pragma unroll
            for (int j = 0; j < TN; ++j) b[j] = Bs[k][tx * TN + j];
#pragma unroll
            for (int i = 0; i < TM; ++i)
#pragma unroll
                for (int j = 0; j < TN; ++j) acc[i][j] += a[i] * b[j];
        }
        __syncthreads();
    }
#pragma unroll
    for (int i = 0; i < TM; ++i) {
        int m = m0 + ty * TM + i;
#pragma unroll
        for (int j = 0; j < TN; ++j) {
            int n = n0 + tx * TN + j;
            if (EPI == 1)
                C[(size_t)m * N + n] = gelu_t(acc[i][j]) * WS[(size_t)m * N + n];
            else
                C[(size_t)m * N + n] = acc[i][j] * scale;
        }
    }
}

// ---------------- wave-uniform top-16 selection helpers ---------------------
// monotone map: f32 -> u32 preserving order (no NaN in inputs)
__device__ __forceinline__ unsigned f2mono(float f)
{
    int b = __float_as_int(f);
    return (unsigned)(b ^ ((b >> 31) | 0x80000000));
}
// count of set bits strictly below my lane
__device__ __forceinline__ int mbcnt64(unsigned long long m)
{
    return __builtin_amdgcn_mbcnt_hi((unsigned)(m >> 32),
           __builtin_amdgcn_mbcnt_lo((unsigned)m, 0));
}

// Select exactly the top-16 of the wave's 256 keys u[0..3] (flat index
// c = lane*4+j), with lax.top_k tie semantics: larger value first; on equal
// value, lower flat index. Bitwise binary search finds tau = 16th-largest
// key (scalar-pipe heavy, ~12cyc dep/step); ties at tau are filled in
// ascending-c order via mbcnt prefix.
__device__ __forceinline__ void select_top16(const unsigned u[4], bool sel[4])
{
    unsigned tau = 0;
    for (int bit = 31; bit >= 0; --bit) {
        unsigned t = tau | (1u << bit);
        int cnt = 0;
#pragma unroll
        for (int j = 0; j < 4; ++j)
            cnt += __popcll(__ballot(u[j] >= t));
        if (cnt >= 16) tau = t;
    }
    bool gt[4], eq[4];
    int n_gt = 0, below = 0;
#pragma unroll
    for (int j = 0; j < 4; ++j) {
        gt[j] = (u[j] > tau);
        eq[j] = (u[j] == tau);
        n_gt  += __popcll(__ballot(gt[j]));
        below += mbcnt64(__ballot(eq[j]));
    }
    const int need = 16 - n_gt;   // >= 1 by construction of tau
    int run = 0;
#pragma unroll
    for (int j = 0; j < 4; ++j) {
        sel[j] = gt[j] || (eq[j] && (below + run) < need);
        run += eq[j] ? 1 : 0;
    }
}

// ---------------- sim + double top-16 + softmax -> atomic wsum --------------
// One wave per (token,head). Stage 1: top-16 of 256 sims, rank-sorted via
// LDS (pk = 16i+j needs ranks). Stage 2: candidates v0[i]+i0[j]; only the
// SET matters (softmax + final sum are order-invariant), so threshold
// selection alone suffices. Softmax weights atomically accumulated into
// wsum[token][expert-position] (pre-zeroed by the q-GEMM kernel).
__global__ __launch_bounds__(256)
void k_simtopk(const float* __restrict__ q, const float* __restrict__ keys,
               float* __restrict__ wsum)
{
    __shared__ float Sv[4][16];   // per-wave: member values (c-order)
    __shared__ int   Sc[4][16];   // per-wave: member flat indices (c-order)
    __shared__ float V0[4][16];   // rank-sorted top-16 values
    __shared__ int   I0[4][16];   // rank-sorted top-16 indices

    const int wid  = threadIdx.x >> 6;                  // wave in block, 0..3
    const int lane = threadIdx.x & 63;
    const int th   = blockIdx.x * 4 + wid;              // token-head 0..8191
    const int t    = th >> 3;
    const int hh   = th & 7;
    const int base = lane * 4;

    // wave-uniform q sub-row (p=0 half): cols hh*32 .. hh*32+31
    const float4* qv = (const float4*)(q + (size_t)t * DIM + hh * DK);
    float4 qr[8];
#pragma unroll
    for (int i = 0; i < 8; ++i) qr[i] = qv[i];

    // 4 keys per lane: k = base + j ;  keys[h][k][0][d]
    float v1[4];
#pragma unroll
    for (int j = 0; j < 4; ++j) {
        const float4* kv = (const float4*)(keys + ((size_t)hh * NKEYS + base + j) * 2 * DK);
        float s = 0.f;
#pragma unroll
        for (int i = 0; i < 8; ++i) {
            float4 kk = kv[i];
            s += kk.x * qr[i].x + kk.y * qr[i].y + kk.z * qr[i].z + kk.w * qr[i].w;
        }
        v1[j] = s;
    }

    // ---- stage 1: top-16 of sims, then rank-sort through LDS ----
    unsigned u1[4];
#pragma unroll
    for (int j = 0; j < 4; ++j) u1[j] = f2mono(v1[j]);
    bool sel1[4];
    select_top16(u1, sel1);

    // compact members to LDS in ascending-c order
    int below = 0;
#pragma unroll
    for (int j = 0; j < 4; ++j) below += mbcnt64(__ballot(sel1[j]));
    int run = 0;
#pragma unroll
    for (int j = 0; j < 4; ++j) {
        if (sel1[j]) { Sv[wid][below + run] = v1[j]; Sc[wid][below + run] = base + j; }
        run += sel1[j] ? 1 : 0;
    }
    __syncthreads();

    // rank each member among the 16 (value desc, tie -> lower index)
    {
        float mv = Sv[wid][lane & 15];
        int   mc = Sc[wid][lane & 15];
        int rank = 0;
#pragma unroll
        for (int k = 0; k < 16; ++k) {
            float ov = Sv[wid][k];
            int   oc = Sc[wid][k];
            rank += (ov > mv || (ov == mv && oc < mc)) ? 1 : 0;
        }
        if (lane < 16) { V0[wid][rank] = mv; I0[wid][rank] = mc; }
    }
    __syncthreads();

    // ---- stage 2: candidates cand(i,j) = v0[i] + i0[j], c = 16i+j = base+jj
    const float v0v = V0[wid][lane >> 2];
    const int4  iv  = *(const int4*)&I0[wid][(lane & 3) * 4];
    float f[4];
    f[0] = v0v + (float)iv.x; f[1] = v0v + (float)iv.y;
    f[2] = v0v + (float)iv.z; f[3] = v0v + (float)iv.w;
    unsigned u2[4];
#pragma unroll
    for (int j = 0; j < 4; ++j) u2[j] = f2mono(f[j]);
    bool sel2[4];
    select_top16(u2, sel2);

    // global max of all candidates = v0[0] + max(i0): lanes {4g..4g+3} cover
    // all 16 i0 entries, so a 2-step xor-reduce within each 4-group suffices.
    int mi = max(max(iv.x, iv.y), max(iv.z, iv.w));
    mi = max(mi, __shfl_xor(mi, 1, 64));
    mi = max(mi, __shfl_xor(mi, 2, 64));
    const float mx = V0[wid][0] + (float)mi;

    float e[4];
    float s = 0.f;
#pragma unroll
    for (int j = 0; j < 4; ++j) {
        e[j] = sel2[j] ? expf(f[j] - mx) : 0.f;
        s += e[j];
    }
#pragma unroll
    for (int off = 32; off; off >>= 1) s += __shfl_xor(s, off, 64);
    const float inv = 1.f / s;

#pragma unroll
    for (int j = 0; j < 4; ++j)
        if (sel2[j])
            atomicAdd(&wsum[(size_t)t * NKEYS + base + j], e[j] * inv);
}

// ---------------- launch ----------------
extern "C" void kernel_launch(void* const* d_in, const int* in_sizes, int n_in,
                              void* d_out, int out_size, void* d_ws, size_t ws_size,
                              hipStream_t stream)
{
    const float* x    = (const float*)d_in[0];   // [1024, 512]
    const float* wq   = (const float*)d_in[1];   // [512, 512]
    const float* keys = (const float*)d_in[2];   // [8, 256, 2, 32]
    const float* wd   = (const float*)d_in[3];   // [65536, 512] (rows 0..255 used)
    const float* wu   = (const float*)d_in[4];   // [65536, 512] (rows 0..255 used)
    float* out = (float*)d_out;                  // [1024, 512]

    float* q    = (float*)d_ws;                  // 1024*512
    float* Cb   = q + NTOK * DIM;                // 1024*256
    float* wsum = Cb + NTOK * NKEYS;             // 1024*256

    const float bnscale = 1.0f / sqrtf(1.0f + 1e-5f);

    // q = (x @ wq) * bnscale  [1024 x 512], K=512; also zeroes wsum (1KB/blk)
    sgemm<32, 64, 64, 2, 4, false, 0, true>
        <<<dim3(DIM / 64, NTOK / 32), 256, 0, stream>>>(x, wq, q, NTOK, DIM, DIM,
                                                        bnscale, wsum);

    // sim + double top-16 + softmax -> atomic accumulate into wsum[t][e]
    k_simtopk<<<dim3(NTOK * HEADS / 4), 256, 0, stream>>>(q, keys, wsum);

    // Cb[t,e] = gelu(q . wd[e]) * wsum[t,e]   [1024 x 256], K=512, B^T
    sgemm<32, 32, 64, 2, 2, true, 1, false>
        <<<dim3(NKEYS / 32, NTOK / 32), 256, 0, stream>>>(q, wd, Cb, NTOK, NKEYS,
                                                          DIM, 1.f, wsum);

    // out = Cb @ wu[0:256]   [1024 x 512], K=256
    sgemm<32, 64, 64, 2, 4, false, 0, false>
        <<<dim3(DIM / 64, NTOK / 32), 256, 0, stream>>>(Cb, wu, out, NTOK, DIM,
                                                        NKEYS, 1.f, wsum);
}

// Round 4
// 289.879 us; speedup vs baseline: 1.5931x; 1.1121x over previous
//
#include <hip/hip_runtime.h>
#include <math.h>

#define DIM    512
#define HEADS  8
#define DK     32
#define NKEYS  256
#define PKTOP  16
#define NTOK   1024   // b*n = 2*512

// gelu (tanh approx, matches flax approximate gelu)
__device__ __forceinline__ float gelu_t(float x)
{
    float x3 = x * x * x;
    return 0.5f * x * (1.f + tanhf(0.7978845608028654f * (x + 0.044715f * x3)));
}

// ---------------- generic fp32 tiled GEMM (round-0 proven structure) --------
// A: [M,K] row-major. B: [K,N] row-major (BT=false) or [N,K] row-major (BT=true).
// EPI==0: C = scale*acc.  EPI==1: C = gelu(acc) * WS[m][n]  (WS is [M,N] rm).
// ZW: block zeroes 1024 floats of WS at offset bid*1024 (wsum init; k1 grid
// is 256 blocks x 1024 floats = the full 1024x256 wsum).
template<int BM, int BN, int BK, int TM, int TN, bool BT, int EPI, bool ZW>
__global__ __launch_bounds__(256)
void sgemm(const float* __restrict__ A, const float* __restrict__ B,
           float* __restrict__ C, int M, int N, int K, float scale,
           float* __restrict__ WS)
{
    __shared__ float As[BK][BM + 4];
    __shared__ float Bs[BK][BN + 4];
    const int tid = threadIdx.x;
    const int tx  = tid & 15;
    const int ty  = tid >> 4;
    const int m0  = blockIdx.y * BM;
    const int n0  = blockIdx.x * BN;

    if (ZW) {
        const int bid = blockIdx.y * gridDim.x + blockIdx.x;
        *(float4*)(WS + (size_t)bid * 1024 + tid * 4) = make_float4(0.f, 0.f, 0.f, 0.f);
    }

    float acc[TM][TN];
#pragma unroll
    for (int i = 0; i < TM; ++i)
#pragma unroll
        for (int j = 0; j < TN; ++j) acc[i][j] = 0.f;

    for (int k0 = 0; k0 < K; k0 += BK) {
        // stage A tile (transposed): As[k][m] = A[m0+m][k0+k]
#pragma unroll
        for (int it = 0; it < (BM * BK / 4) / 256; ++it) {
            int L   = tid + 256 * it;
            int row = L / (BK / 4), kq = L % (BK / 4);
            float4 v = *(const float4*)(A + (size_t)(m0 + row) * K + k0 + kq * 4);
            As[kq * 4 + 0][row] = v.x; As[kq * 4 + 1][row] = v.y;
            As[kq * 4 + 2][row] = v.z; As[kq * 4 + 3][row] = v.w;
        }
        if (!BT) {
#pragma unroll
            for (int it = 0; it < (BK * BN / 4) / 256; ++it) {
                int L = tid + 256 * it;
                int k = L / (BN / 4), nq = L % (BN / 4);
                float4 v = *(const float4*)(B + (size_t)(k0 + k) * N + n0 + nq * 4);
                *(float4*)&Bs[k][nq * 4] = v;
            }
        } else {
#pragma unroll
            for (int it = 0; it < (BN * BK / 4) / 256; ++it) {
                int L = tid + 256 * it;
                int n = L / (BK / 4), kq = L % (BK / 4);
                float4 v = *(const float4*)(B + (size_t)(n0 + n) * K + k0 + kq * 4);
                Bs[kq * 4 + 0][n] = v.x; Bs[kq * 4 + 1][n] = v.y;
                Bs[kq * 4 + 2][n] = v.z; Bs[kq * 4 + 3][n] = v.w;
            }
        }
        __syncthreads();
#pragma unroll
        for (int k = 0; k < BK; ++k) {
            float a[TM], b[TN];
#pragma unroll
            for (int i = 0; i < TM; ++i) a[i] = As[k][ty * TM + i];
#pragma unroll
            for (int j = 0; j < TN; ++j) b[j] = Bs[k][tx * TN + j];
#pragma unroll
            for (int i = 0; i < TM; ++i)
#pragma unroll
                for (int j = 0; j < TN; ++j) acc[i][j] += a[i] * b[j];
        }
        __syncthreads();
    }
#pragma unroll
    for (int i = 0; i < TM; ++i) {
        int m = m0 + ty * TM + i;
#pragma unroll
        for (int j = 0; j < TN; ++j) {
            int n = n0 + tx * TN + j;
            if (EPI == 1)
                C[(size_t)m * N + n] = gelu_t(acc[i][j]) * WS[(size_t)m * N + n];
            else
                C[(size_t)m * N + n] = acc[i][j] * scale;
        }
    }
}

// ---------------- wave-uniform top-16 selection helpers ---------------------
// monotone map: f32 -> u32 preserving order (no NaN in inputs)
__device__ __forceinline__ unsigned f2mono(float f)
{
    int b = __float_as_int(f);
    return (unsigned)(b ^ ((b >> 31) | 0x80000000));
}
// count of set bits strictly below my lane
__device__ __forceinline__ int mbcnt64(unsigned long long m)
{
    return __builtin_amdgcn_mbcnt_hi((unsigned)(m >> 32),
           __builtin_amdgcn_mbcnt_lo((unsigned)m, 0));
}

// Find tau = 16th-largest of the wave's 256 keys u[0..3], and need = number
// of tau-equal elements to keep (lowest flat index first). Early exit when a
// threshold selects exactly 16 (then {u >= tau} IS the top-16 and need covers
// all equals). Selection rule at call site:
//   sel = (u > tau) || (u == tau && tie_rank_in_ascending_c < need)
__device__ __forceinline__ void find_tau(const unsigned u[4],
                                         unsigned &tau_o, int &need_o)
{
    unsigned tau = 0u;
    for (int bit = 31; bit >= 0; --bit) {
        unsigned t = tau | (1u << bit);
        int cnt = 0;
#pragma unroll
        for (int j = 0; j < 4; ++j)
            cnt += __popcll(__ballot(u[j] >= t));
        if (cnt >= 16) {
            tau = t;
            if (cnt == 16) break;   // exact: threshold set == top-16
        }
    }
    int n_gt = 0;
#pragma unroll
    for (int j = 0; j < 4; ++j)
        n_gt += __popcll(__ballot(u[j] > tau));
    need_o = 16 - n_gt;
    tau_o  = tau;
}

// ---------------- sim + double top-16 + softmax -> atomic wsum --------------
// Grid: 8 heads x 64 token-groups. Block (256 thr = 4 waves) stages its
// head's p=0 keys (256 rows x 32 f) into LDS ONCE with coalesced 128B-line
// loads, XOR-swizzled (d ^ ((row&7)*4)) so the per-lane row reads are
// conflict-free ds_read_b128 at natural 128B row stride. Each wave processes
// 4 tokens. Lane owns rows {l, l+64, l+128, l+192} (flat index c = row, so
// ascending c == j-major, lane-minor). Stage 2 candidates keep the
// c = lane*4+jj (lane-major) layout from the verified r3 kernel.
__global__ __launch_bounds__(256)
void k_simtopk(const float* __restrict__ q, const float* __restrict__ keys,
               float* __restrict__ wsum)
{
    __shared__ float Ks[NKEYS][32];   // 32 KB, swizzled columns
    __shared__ float Sv[4][16];       // per-wave: member values (c-order)
    __shared__ int   Sc[4][16];       // per-wave: member flat indices (c-order)
    __shared__ float V0[4][16];       // rank-sorted top-16 values
    __shared__ int   I0[4][16];       // rank-sorted top-16 indices

    const int hh   = blockIdx.x & 7;          // head
    const int tg   = blockIdx.x >> 3;         // token group 0..63
    const int tid  = threadIdx.x;
    const int wid  = tid >> 6;
    const int lane = tid & 63;

    // ---- stage keys[hh][r][0][d] -> Ks[r][d ^ ((r&7)*4)], coalesced ----
#pragma unroll
    for (int it = 0; it < 8; ++it) {
        int idx = it * 1024 + tid * 4;        // flat float index
        int r = idx >> 5, d = idx & 31;       // d multiple of 4
        float4 v = *(const float4*)(keys + ((size_t)hh * NKEYS + r) * 2 * DK + d);
        *(float4*)&Ks[r][d ^ ((r & 7) * 4)] = v;
    }
    __syncthreads();

    const int sw = (lane & 7) * 4;            // row&7 == lane&7 for owned rows

    for (int ti = 0; ti < 4; ++ti) {
        const int t = tg * 16 + wid * 4 + ti;

        // wave-uniform q sub-row (p=0 half): cols hh*32 .. hh*32+31
        const float4* qv = (const float4*)(q + (size_t)t * DIM + hh * DK);
        float4 qr[8];
#pragma unroll
        for (int i = 0; i < 8; ++i) qr[i] = qv[i];

        // sims for rows l+64j from LDS (conflict-free swizzled b128 reads)
        float v1[4];
#pragma unroll
        for (int j = 0; j < 4; ++j) {
            const float* kr = &Ks[lane + 64 * j][0];
            float s = 0.f;
#pragma unroll
            for (int d0 = 0; d0 < 8; ++d0) {
                float4 kk = *(const float4*)&kr[(d0 * 4) ^ sw];
                s += kk.x * qr[d0].x + kk.y * qr[d0].y
                   + kk.z * qr[d0].z + kk.w * qr[d0].w;
            }
            v1[j] = s;
        }

        // ---- stage 1: top-16 of sims (tie order: ascending c = j-major) ----
        unsigned u1[4];
#pragma unroll
        for (int j = 0; j < 4; ++j) u1[j] = f2mono(v1[j]);
        unsigned tau1; int need1;
        find_tau(u1, tau1, need1);

        bool sel1[4];
        {
            int pre = 0;
#pragma unroll
            for (int j = 0; j < 4; ++j) {
                bool gt = u1[j] > tau1, eq = u1[j] == tau1;
                unsigned long long bal = __ballot(eq);
                sel1[j] = gt || (eq && (pre + mbcnt64(bal)) < need1);
                pre += __popcll(bal);
            }
        }
        // compact members to LDS in ascending-c (j-major) order
        {
            int pre = 0;
#pragma unroll
            for (int j = 0; j < 4; ++j) {
                unsigned long long bal = __ballot(sel1[j]);
                int pos = pre + mbcnt64(bal);
                if (sel1[j]) { Sv[wid][pos] = v1[j]; Sc[wid][pos] = lane + 64 * j; }
                pre += __popcll(bal);
            }
        }
        __syncthreads();

        // rank each member among the 16 (value desc, tie -> lower index)
        {
            float mv = Sv[wid][lane & 15];
            int   mc = Sc[wid][lane & 15];
            int rank = 0;
#pragma unroll
            for (int k = 0; k < 16; ++k) {
                float ov = Sv[wid][k];
                int   oc = Sc[wid][k];
                rank += (ov > mv || (ov == mv && oc < mc)) ? 1 : 0;
            }
            if (lane < 16) { V0[wid][rank] = mv; I0[wid][rank] = mc; }
        }
        __syncthreads();

        // ---- stage 2: cand(i,j) = v0[i] + i0[j], c = 16i+j = lane*4+jj ----
        const float v0v = V0[wid][lane >> 2];
        const int4  iv  = *(const int4*)&I0[wid][(lane & 3) * 4];
        float f[4];
        f[0] = v0v + (float)iv.x; f[1] = v0v + (float)iv.y;
        f[2] = v0v + (float)iv.z; f[3] = v0v + (float)iv.w;
        unsigned u2[4];
#pragma unroll
        for (int j = 0; j < 4; ++j) u2[j] = f2mono(f[j]);
        unsigned tau2; int need2;
        find_tau(u2, tau2, need2);

        bool sel2[4];
        {
            bool gt2[4], eq2[4];
            int below = 0;
#pragma unroll
            for (int j = 0; j < 4; ++j) {
                gt2[j] = u2[j] > tau2;
                eq2[j] = u2[j] == tau2;
                below += mbcnt64(__ballot(eq2[j]));
            }
            int run = 0;
#pragma unroll
            for (int j = 0; j < 4; ++j) {
                sel2[j] = gt2[j] || (eq2[j] && (below + run) < need2);
                run += eq2[j] ? 1 : 0;
            }
        }

        // global max of candidates = v0[0] + max(i0): lanes {4g..4g+3} hold
        // all 16 i0 entries -> 2-step xor-reduce within each 4-group.
        int mi = max(max(iv.x, iv.y), max(iv.z, iv.w));
        mi = max(mi, __shfl_xor(mi, 1, 64));
        mi = max(mi, __shfl_xor(mi, 2, 64));
        const float mx = V0[wid][0] + (float)mi;

        float e[4];
        float s = 0.f;
#pragma unroll
        for (int j = 0; j < 4; ++j) {
            e[j] = sel2[j] ? expf(f[j] - mx) : 0.f;
            s += e[j];
        }
#pragma unroll
        for (int off = 32; off; off >>= 1) s += __shfl_xor(s, off, 64);
        const float inv = 1.f / s;

#pragma unroll
        for (int j = 0; j < 4; ++j)
            if (sel2[j])
                atomicAdd(&wsum[(size_t)t * NKEYS + lane * 4 + j], e[j] * inv);
    }
}

// ---------------- launch ----------------
extern "C" void kernel_launch(void* const* d_in, const int* in_sizes, int n_in,
                              void* d_out, int out_size, void* d_ws, size_t ws_size,
                              hipStream_t stream)
{
    const float* x    = (const float*)d_in[0];   // [1024, 512]
    const float* wq   = (const float*)d_in[1];   // [512, 512]
    const float* keys = (const float*)d_in[2];   // [8, 256, 2, 32]
    const float* wd   = (const float*)d_in[3];   // [65536, 512] (rows 0..255 used)
    const float* wu   = (const float*)d_in[4];   // [65536, 512] (rows 0..255 used)
    float* out = (float*)d_out;                  // [1024, 512]

    float* q    = (float*)d_ws;                  // 1024*512
    float* Cb   = q + NTOK * DIM;                // 1024*256
    float* wsum = Cb + NTOK * NKEYS;             // 1024*256

    const float bnscale = 1.0f / sqrtf(1.0f + 1e-5f);

    // q = (x @ wq) * bnscale  [1024 x 512], K=512; also zeroes wsum (1KB/blk)
    sgemm<32, 64, 64, 2, 4, false, 0, true>
        <<<dim3(DIM / 64, NTOK / 32), 256, 0, stream>>>(x, wq, q, NTOK, DIM, DIM,
                                                        bnscale, wsum);

    // sim + double top-16 + softmax -> atomic accumulate into wsum[t][e]
    k_simtopk<<<dim3(HEADS * 64), 256, 0, stream>>>(q, keys, wsum);

    // Cb[t,e] = gelu(q . wd[e]) * wsum[t,e]   [1024 x 256], K=512, B^T
    sgemm<32, 32, 64, 2, 2, true, 1, false>
        <<<dim3(NKEYS / 32, NTOK / 32), 256, 0, stream>>>(q, wd, Cb, NTOK, NKEYS,
                                                          DIM, 1.f, wsum);

    // out = Cb @ wu[0:256]   [1024 x 512], K=256
    sgemm<32, 64, 64, 2, 4, false, 0, false>
        <<<dim3(DIM / 64, NTOK / 32), 256, 0, stream>>>(Cb, wu, out, NTOK, DIM,
                                                        NKEYS, 1.f, wsum);
}